// Round 2
// baseline (807.798 us; speedup 1.0000x reference)
//
#include <hip/hip_runtime.h>
#include <hip/hip_bf16.h>
#include <math.h>

// linearGPT2 cell: B=2048 D=1024 H=16 DH=64 R=32. fp32 I/O, bf16 MFMA compute.
// Pipeline: LN1 -> GEMM(qkv, fp32 out) -> attn core (phi/state/new_s/new_z/head)
//           -> GEMM(proj) -> LN2(+x, bf16+fp32 out) -> GEMM(fc)+GELU
//           -> GEMM(mp)+h2 residual -> out (fp32)

#define Bsz 2048
#define Dm  1024
#define Hh  16
#define DHd 64
#define Rr  32

typedef __bf16 bf16x8 __attribute__((ext_vector_type(8)));
typedef float  f32x4  __attribute__((ext_vector_type(4)));

__device__ __forceinline__ float bf2f(__bf16 x) { return (float)x; }
__device__ __forceinline__ __bf16 f2bf(float x) { return (__bf16)x; }

// ---------------- LayerNorm (optionally fused residual add + fp32 copy) ----
template<bool ADD, typename TA>
__global__ __launch_bounds__(256) void ln_kernel(
    const TA* __restrict__ a, const float* __restrict__ b2,
    const float* __restrict__ g, const float* __restrict__ beta,
    __bf16* __restrict__ outb, float* __restrict__ outf)
{
  const int row = blockIdx.x;
  const int t = threadIdx.x;
  const size_t base = (size_t)row * Dm;
  float vals[4];
#pragma unroll
  for (int i = 0; i < 4; ++i) {
    const int c = t * 4 + i;
    float v = (float)a[base + c];
    if (ADD) v += b2[base + c];
    vals[i] = v;
  }
  float sm = 0.f, sq = 0.f;
#pragma unroll
  for (int i = 0; i < 4; ++i) { sm += vals[i]; sq += vals[i] * vals[i]; }
  for (int off = 32; off > 0; off >>= 1) {
    sm += __shfl_down(sm, off);
    sq += __shfl_down(sq, off);
  }
  __shared__ float smw[4], sqw[4];
  if ((t & 63) == 0) { smw[t >> 6] = sm; sqw[t >> 6] = sq; }
  __syncthreads();
  const float S  = smw[0] + smw[1] + smw[2] + smw[3];
  const float SS = sqw[0] + sqw[1] + sqw[2] + sqw[3];
  const float mean = S * (1.f / Dm);
  const float var  = SS * (1.f / Dm) - mean * mean;
  const float inv  = rsqrtf(var + 1e-3f);
#pragma unroll
  for (int i = 0; i < 4; ++i) {
    const int c = t * 4 + i;
    const float r = g[c] * ((vals[i] - mean) * inv) + beta[c];
    outb[base + c] = f2bf(r);
    if (ADD) outf[base + c] = r;  // fp32 copy for the final residual
  }
}

// ---------------- bf16 MFMA GEMM: C = A[MxK](bf16) @ B[KxN](fp32) + bias ----
// 64x64 tile, BK=32, 4 waves, 16x16x32 mfma. Optional exact GELU / residual.
// OUTF32: write fp32, else bf16.
template<bool GELU, bool RES, bool OUTF32>
__global__ __launch_bounds__(256) void gemm_kernel(
    const __bf16* __restrict__ A, const float* __restrict__ B,
    const float* __restrict__ bias, const float* __restrict__ res,
    void* __restrict__ Cv, int M, int N, int K)
{
  __shared__ __align__(16) __bf16 lsA[64][40];  // [m][k], +8 pad
  __shared__ __align__(16) __bf16 lsB[64][40];  // [n][k] (B tile transposed)
  const int t = threadIdx.x;
  const int wave = t >> 6, lane = t & 63;
  const int quad = lane >> 4, l16 = lane & 15;
  const int bm = blockIdx.x * 64, bn = blockIdx.y * 64;
  f32x4 acc0 = {0.f, 0.f, 0.f, 0.f};
  f32x4 acc1 = {0.f, 0.f, 0.f, 0.f};
  f32x4 acc2 = {0.f, 0.f, 0.f, 0.f};
  f32x4 acc3 = {0.f, 0.f, 0.f, 0.f};
  const int arow = t >> 2, acol = (t & 3) * 8;     // A: 16B per thread
  const int bncol = t & 63, bkrow = (t >> 6) * 8;  // B: 8 fp32 scalar per thread
  const size_t abase = (size_t)(bm + arow) * K + acol;

  for (int kt = 0; kt < K; kt += 32) {
    uint4 av = *(const uint4*)(A + abase + kt);
    *(uint4*)(&lsA[arow][acol]) = av;
#pragma unroll
    for (int j = 0; j < 8; ++j)
      lsB[bncol][bkrow + j] = f2bf(B[(size_t)(kt + bkrow + j) * N + bn + bncol]);
    __syncthreads();
    bf16x8 af  = *(const bf16x8*)(&lsA[wave * 16 + l16][quad * 8]);
    bf16x8 bf0 = *(const bf16x8*)(&lsB[      l16][quad * 8]);
    bf16x8 bf1 = *(const bf16x8*)(&lsB[16 + l16][quad * 8]);
    bf16x8 bf2 = *(const bf16x8*)(&lsB[32 + l16][quad * 8]);
    bf16x8 bf3 = *(const bf16x8*)(&lsB[48 + l16][quad * 8]);
    acc0 = __builtin_amdgcn_mfma_f32_16x16x32_bf16(af, bf0, acc0, 0, 0, 0);
    acc1 = __builtin_amdgcn_mfma_f32_16x16x32_bf16(af, bf1, acc1, 0, 0, 0);
    acc2 = __builtin_amdgcn_mfma_f32_16x16x32_bf16(af, bf2, acc2, 0, 0, 0);
    acc3 = __builtin_amdgcn_mfma_f32_16x16x32_bf16(af, bf3, acc3, 0, 0, 0);
    __syncthreads();
  }

  const int m0 = bm + wave * 16 + quad * 4;
  f32x4 accs[4] = {acc0, acc1, acc2, acc3};
#pragma unroll
  for (int ns = 0; ns < 4; ++ns) {
    const int col = bn + ns * 16 + l16;
    const float bv = bias[col];
#pragma unroll
    for (int i = 0; i < 4; ++i) {
      const int row = m0 + i;
      float v = accs[ns][i] + bv;
      if (GELU) v = 0.5f * v * (1.0f + erff(v * 0.70710678118654752f));
      if (RES) v += res[(size_t)row * N + col];
      if (OUTF32) ((float*)Cv)[(size_t)row * N + col] = v;
      else        ((__bf16*)Cv)[(size_t)row * N + col] = f2bf(v);
    }
  }
}

// ---------------- fused linear-attention core ------------------------------
// one wave per (b,h): phi sigmoids, new_s/new_z (fp32, to d_out), head=num/den
__global__ __launch_bounds__(64) void attn_kernel(
    const float* __restrict__ qkv, const float* __restrict__ s,
    const float* __restrict__ z,
    const float* __restrict__ w1, const float* __restrict__ w2,
    const float* __restrict__ w3, const float* __restrict__ w4,
    float* __restrict__ new_s, float* __restrict__ new_z,
    __bf16* __restrict__ head)
{
  const int bh = blockIdx.x;
  const int b = bh >> 4, h = bh & 15;
  const int tid = threadIdx.x;
  __shared__ float ksh[64], qsh[64];
  __shared__ float phish[4][32];
  __shared__ float nzsh[32];

  const float* qrow = qkv + (size_t)b * (3 * Dm);
  const float qv = qrow[h * 64 + tid];
  const float kv = qrow[Dm + h * 64 + tid];
  const float vv = qrow[2 * Dm + h * 64 + tid];
  qsh[tid] = qv; ksh[tid] = kv;
  __syncthreads();

  {  // 128 dots of length 64: 2 per thread. w[h,d,r] stride 32 over d.
    const int r = tid & 31;
    const float* wm[4] = {w1, w2, w3, w4};
    for (int mm = (tid >> 5); mm < 4; mm += 2) {
      const float* w = wm[mm] + (size_t)h * (DHd * Rr) + r;
      const float* src = (mm < 2) ? ksh : qsh;
      float acc = 0.f;
#pragma unroll 8
      for (int d = 0; d < 64; ++d) acc += src[d] * w[(size_t)d * 32];
      phish[mm][r] = 1.f / (1.f + expf(-acc));
    }
  }
  __syncthreads();

  const size_t zbase = (size_t)b * (Rr * Hh) + h * Rr;
  if (tid < 32) {
    const float nz = z[zbase + tid] + phish[1][tid];
    new_z[zbase + tid] = nz;
    nzsh[tid] = nz;
  }
  __syncthreads();

  float den = 0.f;
#pragma unroll
  for (int r = 0; r < 32; ++r) den += phish[3][r] * nzsh[r];

  const size_t sbase = ((size_t)b * Hh + h) * (Rr * DHd);
  float num = 0.f;
#pragma unroll 4
  for (int r = 0; r < 32; ++r) {
    const float ns = s[sbase + r * 64 + tid] + phish[0][r] * vv;
    new_s[sbase + r * 64 + tid] = ns;
    num += phish[2][r] * ns;
  }
  head[(size_t)b * Dm + h * 64 + tid] = f2bf(num / den);
}

// ---------------------------------------------------------------------------
extern "C" void kernel_launch(void* const* d_in, const int* in_sizes, int n_in,
                              void* d_out, int out_size, void* d_ws, size_t ws_size,
                              hipStream_t stream)
{
  const float* x      = (const float*)d_in[0];
  const float* s_in   = (const float*)d_in[1];
  const float* z_in   = (const float*)d_in[2];
  const float* ln1_g  = (const float*)d_in[3];
  const float* ln1_b  = (const float*)d_in[4];
  const float* ln2_g  = (const float*)d_in[5];
  const float* ln2_b  = (const float*)d_in[6];
  const float* W_attn = (const float*)d_in[7];
  const float* b_attn = (const float*)d_in[8];
  const float* W_proj = (const float*)d_in[9];
  const float* b_proj = (const float*)d_in[10];
  const float* W_fc   = (const float*)d_in[11];
  const float* b_fc   = (const float*)d_in[12];
  const float* W_mp   = (const float*)d_in[13];
  const float* b_mp   = (const float*)d_in[14];
  const float* w1     = (const float*)d_in[15];
  const float* w2     = (const float*)d_in[16];
  const float* w3     = (const float*)d_in[17];
  const float* w4     = (const float*)d_in[18];

  float* out0  = (float*)d_out;                        // [B,D]
  float* out_s = out0 + (size_t)Bsz * Dm;              // [B,D*R]
  float* out_z = out_s + (size_t)Bsz * Dm * Rr;        // [B,R*H]

  char* ws = (char*)d_ws;
  __bf16* h1    = (__bf16*)ws; ws += (size_t)Bsz * Dm * 2;       // 4 MB
  float*  qkv   = (float*) ws; ws += (size_t)Bsz * 3 * Dm * 4;   // 24 MB
  __bf16* headp = (__bf16*)ws; ws += (size_t)Bsz * Dm * 2;       // 4 MB
  __bf16* attnb = (__bf16*)ws; ws += (size_t)Bsz * Dm * 2;       // 4 MB
  __bf16* h2b   = (__bf16*)ws; ws += (size_t)Bsz * Dm * 2;       // 4 MB
  float*  h2f   = (float*) ws; ws += (size_t)Bsz * Dm * 4;       // 8 MB
  __bf16* fcb   = (__bf16*)ws; ws += (size_t)Bsz * 4 * Dm * 2;   // 16 MB

  ln_kernel<false, float><<<Bsz, 256, 0, stream>>>(
      x, nullptr, ln1_g, ln1_b, h1, nullptr);
  gemm_kernel<false, false, true><<<dim3(Bsz / 64, (3 * Dm) / 64), 256, 0, stream>>>(
      h1, W_attn, b_attn, nullptr, qkv, Bsz, 3 * Dm, Dm);
  attn_kernel<<<Bsz * Hh, 64, 0, stream>>>(qkv, s_in, z_in, w1, w2, w3, w4,
                                           out_s, out_z, headp);
  gemm_kernel<false, false, false><<<dim3(Bsz / 64, Dm / 64), 256, 0, stream>>>(
      headp, W_proj, b_proj, nullptr, attnb, Bsz, Dm, Dm);
  ln_kernel<true, __bf16><<<Bsz, 256, 0, stream>>>(
      attnb, x, ln2_g, ln2_b, h2b, h2f);
  gemm_kernel<true, false, false><<<dim3(Bsz / 64, (4 * Dm) / 64), 256, 0, stream>>>(
      h2b, W_fc, b_fc, nullptr, fcb, Bsz, 4 * Dm, Dm);
  gemm_kernel<false, true, true><<<dim3(Bsz / 64, Dm / 64), 256, 0, stream>>>(
      fcb, W_mp, b_mp, h2f, out0, Bsz, Dm, 4 * Dm);
}